// Round 1
// baseline (115.050 us; speedup 1.0000x reference)
//
#include <hip/hip_runtime.h>
#include <hip/hip_bf16.h>

// ---------------------------------------------------------------------------
// Net: 512-step vanilla RNN (HID=2) over batch=65536, then 5-layer MLP head.
// Kernel 1: prep    — repack w2,w3,w4 (fp32 [256][256]) into bf16 MFMA B-fragment order
// Kernel 2: scan    — 1 lane per batch chain, 512 steps, 8-deep prefetch, fast tanh
// Kernel 3: mlp     — fused 5-layer head, bf16 MFMA for the 3x 256x256 layers
// ---------------------------------------------------------------------------

typedef __bf16 bf16_t;
typedef bf16_t bf16x8 __attribute__((ext_vector_type(8)));
typedef float  f32x4  __attribute__((ext_vector_type(4)));

__device__ __forceinline__ bf16_t f2bf(float f) {
    unsigned u = __float_as_uint(f);
    u = u + 0x7FFFu + ((u >> 16) & 1u);   // round-to-nearest-even
    unsigned short s = (unsigned short)(u >> 16);
    return __builtin_bit_cast(bf16_t, s);
}
__device__ __forceinline__ float bf2f(bf16_t b) {
    unsigned short s = __builtin_bit_cast(unsigned short, b);
    return __uint_as_float(((unsigned)s) << 16);
}
__device__ __forceinline__ unsigned pack2bf(float lo, float hi) {
    unsigned a = __builtin_bit_cast(unsigned short, f2bf(lo));
    unsigned b = __builtin_bit_cast(unsigned short, f2bf(hi));
    return a | (b << 16);
}

// tanh(z) = 1 - 2/(1+exp(2z)); exp via fast v_exp. Saturates correctly at +-1.
__device__ __forceinline__ float tanh_fast(float z) {
    float e = __expf(2.0f * z);
    return 1.0f - 2.0f / (e + 1.0f);
}

// ---------------------------------------------------------------------------
// Kernel 1: weight repack.  wf[layer][kt][nt][lane][j] = W_layer[n][k] (bf16)
//   n = nt*16 + (lane&15),  k = kt*32 + (lane>>4)*8 + j
// This is the exact per-lane order the MLP kernel's B-fragment dwordx4 expects.
// ---------------------------------------------------------------------------
__global__ void prep_kernel(const float* __restrict__ w2,
                            const float* __restrict__ w3,
                            const float* __restrict__ w4,
                            bf16_t* __restrict__ wf) {
    int idx = blockIdx.x * 256 + threadIdx.x;      // 0 .. 3*65536-1
    int j     = idx & 7;
    int lane  = (idx >> 3) & 63;
    int nt    = (idx >> 9) & 15;
    int kt    = (idx >> 13) & 7;
    int layer = idx >> 16;
    const float* w = (layer == 0) ? w2 : (layer == 1) ? w3 : w4;
    int n = nt * 16 + (lane & 15);
    int k = kt * 32 + (lane >> 4) * 8 + j;
    wf[idx] = f2bf(w[n * 256 + k]);
}

// ---------------------------------------------------------------------------
// Kernel 2: RNN scan. One lane per batch element.
// x: [512][65536][2] fp32.  Per-wave loads are 64 contiguous float2 = 512 B.
// ---------------------------------------------------------------------------
__global__ __launch_bounds__(256) void scan_kernel(
        const float* __restrict__ x,
        const float* __restrict__ wih, const float* __restrict__ bih,
        const float* __restrict__ whh, const float* __restrict__ bhh,
        float* __restrict__ hout) {
    int b = blockIdx.x * 256 + threadIdx.x;        // batch index, 0..65535
    const float2* xp = reinterpret_cast<const float2*>(x) + b;   // stride 65536 per t

    float w00 = wih[0], w01 = wih[1], w10 = wih[2], w11 = wih[3];
    float u00 = whh[0], u01 = whh[1], u10 = whh[2], u11 = whh[3];
    float c0 = bih[0] + bhh[0];
    float c1 = bih[1] + bhh[1];

    float h0 = 0.0f, h1 = 0.0f;
    float2 buf[8];
#pragma unroll
    for (int p = 0; p < 8; ++p) buf[p] = xp[(size_t)p * 65536];

    // main loop: 63 iterations of 8 steps with prefetch
    for (int t = 0; t < 504; t += 8) {
#pragma unroll
        for (int p = 0; p < 8; ++p) {
            float2 xv = buf[p];
            buf[p] = xp[(size_t)(t + 8 + p) * 65536];
            float z0 = c0 + w00 * xv.x + w01 * xv.y + u00 * h0 + u01 * h1;
            float z1 = c1 + w10 * xv.x + w11 * xv.y + u10 * h0 + u11 * h1;
            h0 = tanh_fast(z0);
            h1 = tanh_fast(z1);
        }
    }
    // tail: last 8 steps, no prefetch
#pragma unroll
    for (int p = 0; p < 8; ++p) {
        float2 xv = buf[p];
        float z0 = c0 + w00 * xv.x + w01 * xv.y + u00 * h0 + u01 * h1;
        float z1 = c1 + w10 * xv.x + w11 * xv.y + u10 * h0 + u11 * h1;
        h0 = tanh_fast(z0);
        h1 = tanh_fast(z1);
    }
    reinterpret_cast<float2*>(hout)[b] = make_float2(h0, h1);
}

// ---------------------------------------------------------------------------
// Kernel 3: fused MLP head. BM=64 rows/block, 256 threads (4 waves, 2x2 tiling).
// LDS: two 64x256 bf16 activation buffers (32 KB each), XOR-swizzled:
//   elem(row,col) at row*256 + (col ^ ((row&7)<<3))   (16-B chunk swizzle)
// Layers 2..4: MFMA 16x16x32_bf16, K-mapping k = kt*32 + 8*(lane>>4) + j
//   (same mapping used for A and B fragments -> result exact regardless of HW
//    internal k order; C/D layout: col=lane&15, row=4*(lane>>4)+i, verified)
// ---------------------------------------------------------------------------
#define BM 64

__device__ __forceinline__ int aswz(int row, int col) {
    return row * 256 + (col ^ ((row & 7) << 3));
}

__global__ __launch_bounds__(256, 2) void mlp_kernel(
        const float* __restrict__ h,
        const bf16_t* __restrict__ wf,
        const float* __restrict__ w1, const float* __restrict__ b1,
        const float* __restrict__ b2, const float* __restrict__ b3,
        const float* __restrict__ b4,
        const float* __restrict__ w5, const float* __restrict__ b5,
        float* __restrict__ out) {
    __shared__ bf16_t Abuf[2][BM * 256];           // 2 x 32 KB

    const int tid  = threadIdx.x;
    const int lane = tid & 63;
    const int wave = tid >> 6;
    const int g    = lane >> 4;                    // 0..3
    const int c    = lane & 15;                    // 0..15
    const int wm   = wave & 1;                     // wave row tile (32 rows)
    const int wn   = wave >> 1;                    // wave col tile (128 cols)
    const int rbase = blockIdx.x * BM;

    // ---- Layer 1: [BM,2] -> [BM,256] on VALU, write bf16 to Abuf[0] ----
    {
        int r    = tid & 63;
        int cseg = tid >> 6;                       // 0..3 -> 64 cols each
        float2 hv = reinterpret_cast<const float2*>(h)[rbase + r];
#pragma unroll 4
        for (int c0 = cseg * 64; c0 < cseg * 64 + 64; c0 += 2) {
            float o0 = b1[c0]     + hv.x * w1[c0 * 2]       + hv.y * w1[c0 * 2 + 1];
            float o1 = b1[c0 + 1] + hv.x * w1[(c0 + 1) * 2] + hv.y * w1[(c0 + 1) * 2 + 1];
            o0 = fmaxf(o0, 0.0f);
            o1 = fmaxf(o1, 0.0f);
            *reinterpret_cast<unsigned*>(&Abuf[0][aswz(r, c0)]) = pack2bf(o0, o1);
        }
    }
    __syncthreads();

    // ---- Layers 2..4: three 256x256 bf16 MFMA layers, ping-pong LDS ----
    for (int l = 0; l < 3; ++l) {
        const int cur = l & 1;                     // 0,1,0
        const int nxt = 1 - cur;
        const bf16_t* wfl = wf + l * 65536;
        const float* bl = (l == 0) ? b2 : (l == 1) ? b3 : b4;

        f32x4 acc[2][8];
#pragma unroll
        for (int ni = 0; ni < 8; ++ni) {
            float bv = bl[wn * 128 + ni * 16 + c];
#pragma unroll
            for (int mi = 0; mi < 2; ++mi)
                acc[mi][ni] = (f32x4){bv, bv, bv, bv};
        }

#pragma unroll
        for (int kt = 0; kt < 8; ++kt) {
            bf16x8 av[2];
#pragma unroll
            for (int mi = 0; mi < 2; ++mi) {
                int row  = wm * 32 + mi * 16 + c;
                int col0 = (kt * 32 + g * 8) ^ ((row & 7) << 3);
                av[mi] = *reinterpret_cast<const bf16x8*>(&Abuf[cur][row * 256 + col0]);
            }
#pragma unroll
            for (int ni = 0; ni < 8; ++ni) {
                bf16x8 bv = *reinterpret_cast<const bf16x8*>(
                    wfl + kt * 8192 + (wn * 8 + ni) * 512 + lane * 8);
#pragma unroll
                for (int mi = 0; mi < 2; ++mi)
                    acc[mi][ni] = __builtin_amdgcn_mfma_f32_16x16x32_bf16(
                        av[mi], bv, acc[mi][ni], 0, 0, 0);
            }
        }

        // epilogue: relu + bf16 + write to other buffer
#pragma unroll
        for (int mi = 0; mi < 2; ++mi) {
#pragma unroll
            for (int ni = 0; ni < 8; ++ni) {
                int r0  = wm * 32 + mi * 16 + g * 4;
                int col = wn * 128 + ni * 16 + c;
#pragma unroll
                for (int i = 0; i < 4; ++i) {
                    float f = fmaxf(acc[mi][ni][i], 0.0f);
                    Abuf[nxt][aswz(r0 + i, col)] = f2bf(f);
                }
            }
        }
        __syncthreads();
    }

    // ---- Layer 5: [BM,256] -> [BM,2] on VALU (final act is in Abuf[1]) ----
    if (tid < 128) {
        int r = tid & 63;
        int o = tid >> 6;                          // output channel 0/1
        const float* w5r = w5 + o * 256;
        float s = b5[o];
#pragma unroll 8
        for (int kt = 0; kt < 256; kt += 8) {
            bf16x8 a = *reinterpret_cast<const bf16x8*>(&Abuf[1][aswz(r, kt)]);
#pragma unroll
            for (int j = 0; j < 8; ++j)
                s += bf2f(a[j]) * w5r[kt + j];
        }
        out[(rbase + r) * 2 + o] = s;
    }
}

// ---------------------------------------------------------------------------
extern "C" void kernel_launch(void* const* d_in, const int* in_sizes, int n_in,
                              void* d_out, int out_size, void* d_ws, size_t ws_size,
                              hipStream_t stream) {
    const float* x    = (const float*)d_in[0];
    const float* wih  = (const float*)d_in[1];
    const float* bih  = (const float*)d_in[2];
    const float* whh  = (const float*)d_in[3];
    const float* bhh  = (const float*)d_in[4];
    const float* w1   = (const float*)d_in[5];
    const float* b1   = (const float*)d_in[6];
    const float* w2   = (const float*)d_in[7];
    const float* b2   = (const float*)d_in[8];
    const float* w3   = (const float*)d_in[9];
    const float* b3   = (const float*)d_in[10];
    const float* w4   = (const float*)d_in[11];
    const float* b4   = (const float*)d_in[12];
    const float* w5   = (const float*)d_in[13];
    const float* b5   = (const float*)d_in[14];
    float* out = (float*)d_out;

    // workspace layout: h [65536][2] fp32 (512 KB) | wf bf16 [3*65536] (384 KB)
    float*  hbuf = (float*)d_ws;
    bf16_t* wfb  = (bf16_t*)((char*)d_ws + 65536 * 2 * sizeof(float));

    prep_kernel<<<768, 256, 0, stream>>>(w2, w3, w4, wfb);
    scan_kernel<<<256, 256, 0, stream>>>(x, wih, bih, whh, bhh, hbuf);
    mlp_kernel<<<1024, 256, 0, stream>>>(hbuf, wfb, w1, b1, b2, b3, b4, w5, b5, out);
}